// Round 9
// baseline (3309.850 us; speedup 1.0000x reference)
//
#include <hip/hip_runtime.h>
#include <cstdint>

#define NPAT 8192
#define NBITS 4096

typedef unsigned int u32;
typedef unsigned short u16;

// ws layout:
//   [0, 4 MiB)      : Bt2[i][t] delta-sign bits, ushort, i in [0,4096), t in [0,512)
//                     thread t: b = t>>3, j = t&7
//                     bit k (k=0..15): sign of d for elem p = 128b + j + 8k
//                     where d = -2*state[i]*W[p][i]  (state = ORIGINAL state; valid
//                     because perm visits each i exactly once). bit set => d<0.
//   [4 MiB, +32 KiB): h0 float[8192] (exact integers)

__global__ void pack_kernel(const float* __restrict__ W, const float* __restrict__ state,
                            u16* __restrict__ Bt2) {
    int b = blockIdx.x & 63;                         // block-of-128 rows
    int i = (blockIdx.x >> 6) * 256 + threadIdx.x;   // column
    uint32_t spre = (__float_as_uint(state[i]) >> 31) ^ 1u;
    uint32_t acc0 = 0, acc1 = 0, acc2 = 0, acc3 = 0;
    const float* base = W + (size_t)(128 * b) * NBITS + i;
    #pragma unroll
    for (int q = 0; q < 128; ++q) {
        uint32_t bit = (__float_as_uint(base[(size_t)q * NBITS]) >> 31) ^ spre;  // coalesced
        int j = q & 7, k = q >> 3;
        uint32_t add = bit << (k + 16 * (j & 1));
        int w = j >> 1;
        if (w == 0) acc0 |= add;
        else if (w == 1) acc1 |= add;
        else if (w == 2) acc2 |= add;
        else acc3 |= add;
    }
    // uint4 = ushorts [8b .. 8b+7] of row i  (u32 w holds j=2w lo, j=2w+1 hi)
    *(uint4*)((char*)Bt2 + (size_t)i * 1024 + b * 16) = make_uint4(acc0, acc1, acc2, acc3);
}

__global__ void gemv_kernel(const float* __restrict__ W, const float* __restrict__ state,
                            float* __restrict__ h0) {
    int wid = threadIdx.x >> 6, lane = threadIdx.x & 63;
    int p = blockIdx.x * 4 + wid;
    const float* row = W + (size_t)p * NBITS;
    float acc = 0.f;
    for (int k = lane; k < NBITS; k += 64) acc += row[k] * state[k];
    #pragma unroll
    for (int d = 1; d < 64; d <<= 1) acc += __shfl_xor(acc, d, 64);
    if (lane == 0) h0[p] = acc;
}

// Exact numpy-pairwise tree, 6 in-wave stages (same instruction sequence proven
// bit-exact R3-R8; here input = one full accumulator chain r_j per lane):
//   stages pair j^1, j^2, j^4(^7), b^1(^15), b^2(^16), b^4(^32) — each partner
//   group holds an identical copy of the needed subtree sum.
__device__ __forceinline__ float tree_reduce(float x) {
    x = __uint_as_float(__builtin_amdgcn_update_dpp(__float_as_uint(x), __float_as_uint(x),
                                                    0xB1, 0xf, 0xf, false)) + x;   // j^1
    x = __uint_as_float(__builtin_amdgcn_update_dpp(__float_as_uint(x), __float_as_uint(x),
                                                    0x4E, 0xf, 0xf, false)) + x;   // j^2
    x = __uint_as_float(__builtin_amdgcn_update_dpp(__float_as_uint(x), __float_as_uint(x),
                                                    0x141, 0xf, 0xf, false)) + x;  // j^4 (half_mirror)
    x = __uint_as_float(__builtin_amdgcn_update_dpp(__float_as_uint(x), __float_as_uint(x),
                                                    0x140, 0xf, 0xf, false)) + x;  // b^1 (mirror)
#if __has_builtin(__builtin_amdgcn_permlane16_swap)
    {
        auto pr = __builtin_amdgcn_permlane16_swap(__float_as_uint(x), __float_as_uint(x),
                                                   false, false);
        x = __uint_as_float(pr[0]) + __uint_as_float(pr[1]);                        // b^2
    }
#else
    x = __int_as_float(__builtin_amdgcn_ds_swizzle(__float_as_int(x), 0x401F)) + x;
#endif
#if __has_builtin(__builtin_amdgcn_permlane32_swap)
    {
        auto pr = __builtin_amdgcn_permlane32_swap(__float_as_uint(x), __float_as_uint(x),
                                                   false, false);
        x = __uint_as_float(pr[0]) + __uint_as_float(pr[1]);                        // b^4
    }
#else
    x += __shfl_xor(x, 32, 64);
#endif
    return x;
}

// decode one +/-2.0f from bit k of (zero-extended ushort) word w
#define DLO(w, k) __uint_as_float((((w) << (31 - (k))) & 0x80000000u) | 0x40000000u)

__launch_bounds__(512, 1)
__global__ void seq_kernel(const u16* __restrict__ Bt2, const float* __restrict__ h0,
                           const float* __restrict__ state, const int* __restrict__ perm,
                           float* __restrict__ out) {
    __shared__ alignas(16) float4 part[2][8];     // [buf][wave] = (Ra,Rb,Rc,0)
    __shared__ alignas(16) float4 part0[8];
    __shared__ alignas(16) int2 pv[NBITS];        // (i, bits(state[i])) in visit order

    const int t = threadIdx.x;
    const int b = t >> 3, j = t & 7;
    const int lane = t & 63, wid = t >> 6;

    for (int q = t; q < NBITS; q += 512) {
        int ii = perm[q];
        pv[q] = make_int2(ii, __float_as_int(state[ii]));
    }

    float h[16];
    #pragma unroll
    for (int k = 0; k < 16; ++k) h[k] = h0[128 * b + j + 8 * k];

    __syncthreads();

    // words for rounds 0,1 (steps 0..3); slot r&1 holds round r's pair
    u32 wA[2], wB[2];
    wA[0] = Bt2[(size_t)pv[0].x * 512 + t];
    wB[0] = Bt2[(size_t)pv[1].x * 512 + t];
    wA[1] = Bt2[(size_t)pv[2].x * 512 + t];
    wB[1] = Bt2[(size_t)pv[3].x * 512 + t];

    float Sprev;
    {   // S(h_0), numpy-exact
        float r;
        #pragma unroll
        for (int k = 0; k < 16; ++k) {
            float x = fmaxf(h[k], 0.f);
            r = k ? fmaf(x, x, r) : x * x;
        }
        float red = tree_reduce(r);
        if (lane == 0) part0[wid] = make_float4(red, 0.f, 0.f, 0.f);
        asm volatile("s_waitcnt lgkmcnt(0)\n\ts_barrier" ::: "memory");
        float4 p0 = part0[0], p1 = part0[1], p2 = part0[2], p3 = part0[3];
        float4 p4 = part0[4], p5 = part0[5], p6 = part0[6], p7 = part0[7];
        Sprev = ((p0.x + p1.x) + (p2.x + p3.x)) + ((p4.x + p5.x) + (p6.x + p7.x));
    }

    for (int rb = 0; rb < NBITS / 2; rb += 2) {
        #pragma unroll
        for (int u = 0; u < 2; ++u) {
            const int rr = rb + u;             // round = steps (2rr, 2rr+1)
            const int s  = 2 * rr;
            const u32 w0 = wA[u], w1 = wB[u];

            // this round's (i0,v0,i1,v1) — one ds_read_b128 (wave broadcast)
            int4 pvc = *(const int4*)(&pv[s]);

            // 3 candidates, inline decode, scalar chains (numpy order, k ascending)
            float ra, rbv, rc;
            #pragma unroll
            for (int k = 0; k < 16; ++k) {
                float d0 = DLO(w0, k);
                float d1 = DLO(w1, k);
                float va = h[k] + d0;
                float vb = h[k] + d1;
                float vc = va + d1;                       // == ref association (exact ints)
                float xa = fmaxf(va, 0.f), xb = fmaxf(vb, 0.f), xc = fmaxf(vc, 0.f);
                if (k == 0) { ra = xa * xa; rbv = xb * xb; rc = xc * xc; }
                else {
                    ra  = fmaf(xa, xa, ra);
                    rbv = fmaf(xb, xb, rbv);
                    rc  = fmaf(xc, xc, rc);
                }
            }
            float Ra = tree_reduce(ra);
            float Rb = tree_reduce(rbv);
            float Rc = tree_reduce(rc);
            if (lane == 0) part[u][wid] = make_float4(Ra, Rb, Rc, 0.f);
            asm volatile("s_waitcnt lgkmcnt(0)\n\ts_barrier" ::: "memory");

            // part reads issued first ...
            float4 p0 = part[u][0], p1 = part[u][1], p2 = part[u][2], p3 = part[u][3];
            float4 p4 = part[u][4], p5 = part[u][5], p6 = part[u][6], p7 = part[u][7];

            // ... refill slot u with round rr+2's words under the LDS latency
            int li = (s + 4 < NBITS) ? s + 4 : NBITS - 2;   // even -> 16B aligned
            int4 pvn = *(const int4*)(&pv[li]);
            wA[u] = Bt2[(size_t)pvn.x * 512 + t];
            wB[u] = Bt2[(size_t)pvn.z * 512 + t];

            // combine (vector adds; per-component association = verified tree)
            float4 sL = make_float4(p0.x + p1.x, p0.y + p1.y, p0.z + p1.z, 0.f);
            float4 sM = make_float4(p2.x + p3.x, p2.y + p3.y, p2.z + p3.z, 0.f);
            float4 sN = make_float4(p4.x + p5.x, p4.y + p5.y, p4.z + p5.z, 0.f);
            float4 sO = make_float4(p6.x + p7.x, p6.y + p7.y, p6.z + p7.z, 0.f);
            float Sa = (sL.x + sM.x) + (sN.x + sO.x);
            float Sb = (sL.y + sM.y) + (sN.y + sO.y);
            float Sc = (sL.z + sM.z) + (sN.z + sO.z);

            // accept iff E_new < E_prev  <=>  S_new > S_prev (ties reject)
            bool acc0 = Sa > Sprev;
            bool acc1 = acc0 ? (Sc > Sa) : (Sb > Sprev);
            Sprev = acc1 ? (acc0 ? Sc : Sb) : (acc0 ? Sa : Sprev);

            if (t == 0) {
                float v0 = __int_as_float(pvc.y), v1 = __int_as_float(pvc.w);
                out[pvc.x] = acc0 ? -v0 : v0;
                out[pvc.z] = acc1 ? -v1 : v1;
            }

            // h-update: wave-uniform accept flags -> scalar branches; skipped on reject.
            // Recomputed deltas are bit-identical (+/-2); integer adds exact, any order.
            int a0 = __builtin_amdgcn_readfirstlane(acc0 ? 1 : 0);
            int a1 = __builtin_amdgcn_readfirstlane(acc1 ? 1 : 0);
            if (a0) {
                if (a1) {
                    #pragma unroll
                    for (int k = 0; k < 16; ++k) h[k] = (h[k] + DLO(w0, k)) + DLO(w1, k);
                } else {
                    #pragma unroll
                    for (int k = 0; k < 16; ++k) h[k] = h[k] + DLO(w0, k);
                }
            } else if (a1) {
                #pragma unroll
                for (int k = 0; k < 16; ++k) h[k] = h[k] + DLO(w1, k);
            }
        }
    }
}

extern "C" void kernel_launch(void* const* d_in, const int* in_sizes, int n_in,
                              void* d_out, int out_size, void* d_ws, size_t ws_size,
                              hipStream_t stream) {
    const float* W     = (const float*)d_in[0];
    const float* state = (const float*)d_in[1];
    const int*   perm  = (const int*)d_in[2];
    float*       out   = (float*)d_out;

    u16*   Bt2 = (u16*)d_ws;
    float* h0  = (float*)((char*)d_ws + (size_t)4096 * 1024);

    pack_kernel<<<1024, 256, 0, stream>>>(W, state, Bt2);
    gemv_kernel<<<2048, 256, 0, stream>>>(W, state, h0);
    seq_kernel<<<1, 512, 0, stream>>>(Bt2, h0, state, perm, out);
}

// Round 10
// 2983.894 us; speedup vs baseline: 1.1092x; 1.1092x over previous
//
#include <hip/hip_runtime.h>
#include <cstdint>

#define NPAT 8192
#define NBITS 4096

typedef float f32x2 __attribute__((ext_vector_type(2)));
typedef unsigned int u32;

// ws layout:
//   [0, 4 MiB)      : Bt[i][t] delta-sign bits, uint32, i in [0,4096), t in [0,256)
//                     thread t: b = t>>2, a = t&3
//                     bit k     (k=0..15): sign of d for elem p = 128b + 2a     + 8k
//                     bit 16+k           : sign of d for elem p = 128b + 2a + 1 + 8k
//                     where d = -2*state[i]*W[p][i]  (state = ORIGINAL state; valid
//                     because perm visits each i exactly once). sign bit set => d<0.
//   [4 MiB, +32 KiB): h0 float[8192] (exact integers)

__global__ void pack_kernel(const float* __restrict__ W, const float* __restrict__ state,
                            uint32_t* __restrict__ Bt) {
    int b = blockIdx.x & 63;
    int i = (blockIdx.x >> 6) * 256 + threadIdx.x;
    uint32_t spre = (__float_as_uint(state[i]) >> 31) ^ 1u;
    uint32_t wd0 = 0, wd1 = 0, wd2 = 0, wd3 = 0;
    const float* base = W + (size_t)(128 * b) * NBITS + i;
    #pragma unroll
    for (int q = 0; q < 128; ++q) {
        uint32_t bit = (__float_as_uint(base[(size_t)q * NBITS]) >> 31) ^ spre;  // coalesced
        int j = q & 7, k = q >> 3;
        int a = j >> 1, hi = j & 1;
        uint32_t add = bit << (16 * hi + k);
        if (a == 0) wd0 |= add;
        else if (a == 1) wd1 |= add;
        else if (a == 2) wd2 |= add;
        else wd3 |= add;
    }
    *(uint4*)(Bt + (size_t)i * 256 + 4 * b) = make_uint4(wd0, wd1, wd2, wd3);
}

__global__ void gemv_kernel(const float* __restrict__ W, const float* __restrict__ state,
                            float* __restrict__ h0) {
    int wid = threadIdx.x >> 6, lane = threadIdx.x & 63;
    int p = blockIdx.x * 4 + wid;
    const float* row = W + (size_t)p * NBITS;
    float acc = 0.f;
    for (int k = lane; k < NBITS; k += 64) acc += row[k] * state[k];
    #pragma unroll
    for (int d = 1; d < 64; d <<= 1) acc += __shfl_xor(acc, d, 64);
    if (lane == 0) h0[p] = acc;
}

// Exact numpy-pairwise tree (proven bit-exact R1-R9, absmax 0).
__device__ __forceinline__ float tree_reduce(float x) {
    x = __uint_as_float(__builtin_amdgcn_update_dpp(__float_as_uint(x), __float_as_uint(x),
                                                    0xB1, 0xf, 0xf, false)) + x;   // quad xor1
    x = __uint_as_float(__builtin_amdgcn_update_dpp(__float_as_uint(x), __float_as_uint(x),
                                                    0x4E, 0xf, 0xf, false)) + x;   // quad xor2
    x = __uint_as_float(__builtin_amdgcn_update_dpp(__float_as_uint(x), __float_as_uint(x),
                                                    0x141, 0xf, 0xf, false)) + x;  // b^1
    x = __uint_as_float(__builtin_amdgcn_update_dpp(__float_as_uint(x), __float_as_uint(x),
                                                    0x140, 0xf, 0xf, false)) + x;  // b^2
#if __has_builtin(__builtin_amdgcn_permlane16_swap)
    {
        auto pr = __builtin_amdgcn_permlane16_swap(__float_as_uint(x), __float_as_uint(x),
                                                   false, false);
        x = __uint_as_float(pr[0]) + __uint_as_float(pr[1]);                        // lane^16
    }
#else
    x = __int_as_float(__builtin_amdgcn_ds_swizzle(__float_as_int(x), 0x401F)) + x;
#endif
#if __has_builtin(__builtin_amdgcn_permlane32_swap)
    {
        auto pr = __builtin_amdgcn_permlane32_swap(__float_as_uint(x), __float_as_uint(x),
                                                   false, false);
        x = __uint_as_float(pr[0]) + __uint_as_float(pr[1]);                        // lane^32
    }
#else
    x += __shfl_xor(x, 32, 64);
#endif
    return x;
}

__device__ __forceinline__ f32x2 pkmax0(f32x2 v) {
    f32x2 z = {0.0f, 0.0f};
    return __builtin_elementwise_max(v, z);
}

#define DLO(w, k) __uint_as_float((((w) << (31 - (k))) & 0x80000000u) | 0x40000000u)
#define DHI(w, k) __uint_as_float((((w) << (15 - (k))) & 0x80000000u) | 0x40000000u)

#define GEN_D(dst, w)                                                       \
    _Pragma("unroll")                                                       \
    for (int k = 0; k < 16; ++k) {                                          \
        dst[k] = (f32x2){DLO(w, k), DHI(w, k)};                             \
    }

// 3 candidates A=h+d0, B=h+d1, C=(h+d0)+d1 (ref association; all exact ints),
// numpy accumulator order (k ascending), then the verified in-wave tree.
#define CHAINS(RA, RB, RC)                                                  \
    {                                                                       \
        f32x2 ra_, rb_, rc_;                                                \
        _Pragma("unroll")                                                   \
        for (int k = 0; k < 16; ++k) {                                      \
            f32x2 va = h[k] + d0[k];                                        \
            f32x2 vb = h[k] + d1[k];                                        \
            f32x2 vc = va + d1[k];                                          \
            f32x2 xa = pkmax0(va), xb = pkmax0(vb), xc = pkmax0(vc);        \
            if (k == 0) { ra_ = xa * xa; rb_ = xb * xb; rc_ = xc * xc; }    \
            else {                                                          \
                ra_ = __builtin_elementwise_fma(xa, xa, ra_);               \
                rb_ = __builtin_elementwise_fma(xb, xb, rb_);               \
                rc_ = __builtin_elementwise_fma(xc, xc, rc_);               \
            }                                                               \
        }                                                                   \
        RA = tree_reduce(ra_.x + ra_.y);                                    \
        RB = tree_reduce(rb_.x + rb_.y);                                    \
        RC = tree_reduce(rc_.x + rc_.y);                                    \
    }

__launch_bounds__(256, 1)
__global__ void seq_kernel(const uint32_t* __restrict__ Bt, const float* __restrict__ h0,
                           const float* __restrict__ state, const int* __restrict__ perm,
                           float* __restrict__ out) {
    __shared__ alignas(16) float part[2][4][4];   // [buf][wave][cand A,B,C,pad]
    __shared__ alignas(16) float part0[4];
    __shared__ alignas(16) int2 pv[NBITS];        // (i, bits(state[i])) in visit order

    const int t = threadIdx.x;
    const int b = t >> 2, a = t & 3;
    const int lane = t & 63, wid = t >> 6;

    for (int q = t; q < NBITS; q += 256) {
        int ii = perm[q];
        pv[q] = make_int2(ii, __float_as_int(state[ii]));
    }

    f32x2 h[16];
    #pragma unroll
    for (int k = 0; k < 16; ++k) h[k] = *(const f32x2*)(h0 + 128 * b + 2 * a + 8 * k);

    __syncthreads();

    // wc = words(round 0) [update source], wn = words(round 1) [spec source]
    u32 wc0 = Bt[(size_t)pv[0].x * 256 + t];
    u32 wc1 = Bt[(size_t)pv[1].x * 256 + t];
    u32 wn0 = Bt[(size_t)pv[2].x * 256 + t];
    u32 wn1 = Bt[(size_t)pv[3].x * 256 + t];

    float Sprev;
    {   // S(h_0), numpy-exact (separate buffer; no same-buf race with round 0)
        f32x2 r;
        #pragma unroll
        for (int k = 0; k < 16; ++k) {
            f32x2 x = pkmax0(h[k]);
            r = (k == 0) ? x * x : __builtin_elementwise_fma(x, x, r);
        }
        float red = tree_reduce(r.x + r.y);
        if (lane == 0) part0[wid] = red;
        asm volatile("s_waitcnt lgkmcnt(0)\n\ts_barrier" ::: "memory");
        Sprev = (part0[0] + part0[1]) + (part0[2] + part0[3]);
    }

    // round-0 trees (exact; h not yet modified)
    float Ra, Rb, Rc;
    f32x2 d0[16], d1[16];
    GEN_D(d0, wc0);
    GEN_D(d1, wc1);
    CHAINS(Ra, Rb, Rc);

    for (int rb = 0; rb < NBITS / 2; rb += 2) {
        #pragma unroll
        for (int u = 0; u < 2; ++u) {
            const int rr = rb + u;             // round = steps (2rr, 2rr+1)
            const int s  = 2 * rr;

            // submit round rr's trees; one lgkm-only barrier per round
            if (lane == 0)
                *(float4*)(&part[u][wid][0]) = make_float4(Ra, Rb, Rc, 0.0f);
            asm volatile("s_waitcnt lgkmcnt(0)\n\ts_barrier" ::: "memory");

            // --- post-barrier window: everything below the barrier, above the
            // decide, is decision-independent and fills the LDS-return latency ---
            float4 p0 = *(const float4*)(&part[u][0][0]);
            float4 p1 = *(const float4*)(&part[u][1][0]);
            float4 p2 = *(const float4*)(&part[u][2][0]);
            float4 p3 = *(const float4*)(&part[u][3][0]);

            int4 pvc = *(const int4*)(&pv[s]);              // (i0,v0,i1,v1), s even
            int li = (s + 4 < NBITS) ? s + 4 : NBITS - 2;
            int4 pvn = *(const int4*)(&pv[li]);
            u32 wf0 = Bt[(size_t)pvn.x * 256 + t];          // words(rr+2), 1-round slack
            u32 wf1 = Bt[(size_t)pvn.z * 256 + t];

            // SPECULATIVE trees(rr+1): assume reject-both (h unchanged) — the
            // common case. Deltas(rr+1) stay live for the redo path.
            GEN_D(d0, wn0);
            GEN_D(d1, wn1);
            float nRa, nRb, nRc;
            CHAINS(nRa, nRb, nRc);

            // pin the speculative block above the uniform branch
            __builtin_amdgcn_sched_barrier(0);

            // decide round rr (every thread redundantly; ties reject)
            float Sa = (p0.x + p1.x) + (p2.x + p3.x);
            float Sb = (p0.y + p1.y) + (p2.y + p3.y);
            float Sc = (p0.z + p1.z) + (p2.z + p3.z);
            bool acc0 = Sa > Sprev;
            bool acc1 = acc0 ? (Sc > Sa) : (Sb > Sprev);
            Sprev = acc1 ? (acc0 ? Sc : Sb) : (acc0 ? Sa : Sprev);

            if (t == 0) {
                float v0 = __int_as_float(pvc.y), v1 = __int_as_float(pvc.w);
                out[pvc.x] = acc0 ? -v0 : v0;               // each i exactly once
                out[pvc.z] = acc1 ? -v1 : v1;
            }

            // accept path (wave-uniform, minority of rounds): update h by
            // re-decoding round rr's words (bit-identical +/-2; exact adds in
            // ref association), then REDO trees(rr+1) with the updated h.
            int a0 = __builtin_amdgcn_readfirstlane(acc0 ? 1 : 0);
            int a1 = __builtin_amdgcn_readfirstlane(acc1 ? 1 : 0);
            if (a0 | a1) {
                if (a0 & a1) {
                    #pragma unroll
                    for (int k = 0; k < 16; ++k) {
                        f32x2 e0 = (f32x2){DLO(wc0, k), DHI(wc0, k)};
                        f32x2 e1 = (f32x2){DLO(wc1, k), DHI(wc1, k)};
                        h[k] = (h[k] + e0) + e1;
                    }
                } else if (a0) {
                    #pragma unroll
                    for (int k = 0; k < 16; ++k)
                        h[k] = h[k] + (f32x2){DLO(wc0, k), DHI(wc0, k)};
                } else {
                    #pragma unroll
                    for (int k = 0; k < 16; ++k)
                        h[k] = h[k] + (f32x2){DLO(wc1, k), DHI(wc1, k)};
                }
                CHAINS(nRa, nRb, nRc);                      // redo with true h
            }

            // rotate pipelines
            wc0 = wn0; wc1 = wn1;
            wn0 = wf0; wn1 = wf1;
            Ra = nRa; Rb = nRb; Rc = nRc;
        }
    }
}

extern "C" void kernel_launch(void* const* d_in, const int* in_sizes, int n_in,
                              void* d_out, int out_size, void* d_ws, size_t ws_size,
                              hipStream_t stream) {
    const float* W     = (const float*)d_in[0];
    const float* state = (const float*)d_in[1];
    const int*   perm  = (const int*)d_in[2];
    float*       out   = (float*)d_out;

    uint32_t* Bt = (uint32_t*)d_ws;
    float*    h0 = (float*)((char*)d_ws + (size_t)4096 * 256 * 4);

    pack_kernel<<<1024, 256, 0, stream>>>(W, state, Bt);
    gemv_kernel<<<2048, 256, 0, stream>>>(W, state, h0);
    seq_kernel<<<1, 256, 0, stream>>>(Bt, h0, state, perm, out);
}

// Round 11
// 2344.357 us; speedup vs baseline: 1.4118x; 1.2728x over previous
//
#include <hip/hip_runtime.h>
#include <cstdint>

#define NPAT 8192
#define NBITS 4096

typedef float f32x2 __attribute__((ext_vector_type(2)));
typedef unsigned int u32;

// ws layout:
//   [0, 4 MiB)      : Bt[i][t] delta-sign bits, uint32, i in [0,4096), t in [0,256)
//                     thread t: b = t>>2, a = t&3
//                     bit k     (k=0..15): sign of d for elem p = 128b + 2a     + 8k
//                     bit 16+k           : sign of d for elem p = 128b + 2a + 1 + 8k
//                     where d = -2*state[i]*W[p][i]  (state = ORIGINAL state; valid
//                     because perm visits each i exactly once). sign bit set => d<0.
//   [4 MiB, +32 KiB): h0 float[8192] (exact integers)

__global__ void pack_kernel(const float* __restrict__ W, const float* __restrict__ state,
                            uint32_t* __restrict__ Bt) {
    int b = blockIdx.x & 63;
    int i = (blockIdx.x >> 6) * 256 + threadIdx.x;
    uint32_t spre = (__float_as_uint(state[i]) >> 31) ^ 1u;
    uint32_t wd0 = 0, wd1 = 0, wd2 = 0, wd3 = 0;
    const float* base = W + (size_t)(128 * b) * NBITS + i;
    #pragma unroll
    for (int q = 0; q < 128; ++q) {
        uint32_t bit = (__float_as_uint(base[(size_t)q * NBITS]) >> 31) ^ spre;  // coalesced
        int j = q & 7, k = q >> 3;
        int a = j >> 1, hi = j & 1;
        uint32_t add = bit << (16 * hi + k);
        if (a == 0) wd0 |= add;
        else if (a == 1) wd1 |= add;
        else if (a == 2) wd2 |= add;
        else wd3 |= add;
    }
    *(uint4*)(Bt + (size_t)i * 256 + 4 * b) = make_uint4(wd0, wd1, wd2, wd3);
}

__global__ void gemv_kernel(const float* __restrict__ W, const float* __restrict__ state,
                            float* __restrict__ h0) {
    int wid = threadIdx.x >> 6, lane = threadIdx.x & 63;
    int p = blockIdx.x * 4 + wid;
    const float* row = W + (size_t)p * NBITS;
    float acc = 0.f;
    for (int k = lane; k < NBITS; k += 64) acc += row[k] * state[k];
    #pragma unroll
    for (int d = 1; d < 64; d <<= 1) acc += __shfl_xor(acc, d, 64);
    if (lane == 0) h0[p] = acc;
}

// Exact numpy-pairwise tree (proven bit-exact R1-R10, absmax 0).
__device__ __forceinline__ float tree_reduce(float x) {
    x = __uint_as_float(__builtin_amdgcn_update_dpp(__float_as_uint(x), __float_as_uint(x),
                                                    0xB1, 0xf, 0xf, false)) + x;   // quad xor1
    x = __uint_as_float(__builtin_amdgcn_update_dpp(__float_as_uint(x), __float_as_uint(x),
                                                    0x4E, 0xf, 0xf, false)) + x;   // quad xor2
    x = __uint_as_float(__builtin_amdgcn_update_dpp(__float_as_uint(x), __float_as_uint(x),
                                                    0x141, 0xf, 0xf, false)) + x;  // b^1
    x = __uint_as_float(__builtin_amdgcn_update_dpp(__float_as_uint(x), __float_as_uint(x),
                                                    0x140, 0xf, 0xf, false)) + x;  // b^2
#if __has_builtin(__builtin_amdgcn_permlane16_swap)
    {
        auto pr = __builtin_amdgcn_permlane16_swap(__float_as_uint(x), __float_as_uint(x),
                                                   false, false);
        x = __uint_as_float(pr[0]) + __uint_as_float(pr[1]);                        // lane^16
    }
#else
    x = __int_as_float(__builtin_amdgcn_ds_swizzle(__float_as_int(x), 0x401F)) + x;
#endif
#if __has_builtin(__builtin_amdgcn_permlane32_swap)
    {
        auto pr = __builtin_amdgcn_permlane32_swap(__float_as_uint(x), __float_as_uint(x),
                                                   false, false);
        x = __uint_as_float(pr[0]) + __uint_as_float(pr[1]);                        // lane^32
    }
#else
    x += __shfl_xor(x, 32, 64);
#endif
    return x;
}

__device__ __forceinline__ f32x2 pkmax0(f32x2 v) {
    f32x2 z = {0.0f, 0.0f};
    return __builtin_elementwise_max(v, z);
}

#define DLO(w, k) __uint_as_float((((w) << (31 - (k))) & 0x80000000u) | 0x40000000u)
#define DHI(w, k) __uint_as_float((((w) << (15 - (k))) & 0x80000000u) | 0x40000000u)

#define GEN_D(dst, w)                                                       \
    _Pragma("unroll")                                                       \
    for (int k = 0; k < 16; ++k) {                                          \
        dst[k] = (f32x2){DLO(w, k), DHI(w, k)};                             \
    }

__launch_bounds__(256, 1)
__global__ void seq_kernel(const uint32_t* __restrict__ Bt, const float* __restrict__ h0,
                           const float* __restrict__ state, const int* __restrict__ perm,
                           float* __restrict__ out) {
    __shared__ alignas(16) float part[2][3][4];   // [buf][cand A,B,C][wave]
    __shared__ alignas(16) float part0[4];
    __shared__ alignas(16) int2 pv[NBITS];        // (i, bits(state[i])) in visit order

    const int t = threadIdx.x;
    const int b = t >> 2, a = t & 3;
    const int lane = t & 63, wid = t >> 6;

    for (int q = t; q < NBITS; q += 256) {
        int ii = perm[q];
        pv[q] = make_int2(ii, __float_as_int(state[ii]));
    }

    f32x2 h[16];
    #pragma unroll
    for (int k = 0; k < 16; ++k) h[k] = *(const f32x2*)(h0 + 128 * b + 2 * a + 8 * k);

    __syncthreads();

    // 2-deep word pipeline: slot r&1 holds round r's pair (refilled 2 rounds ahead)
    u32 wA[2], wB[2];
    wA[0] = Bt[(size_t)pv[0].x * 256 + t];
    wB[0] = Bt[(size_t)pv[1].x * 256 + t];
    wA[1] = Bt[(size_t)pv[2].x * 256 + t];
    wB[1] = Bt[(size_t)pv[3].x * 256 + t];

    f32x2 d0[2][16], d1[16];
    GEN_D(d0[0], wA[0]);           // round 0 deltas
    GEN_D(d1, wB[0]);

    float Sprev;
    {   // S(h_0), numpy-exact; separate buffer (no race with round 0's part[0])
        f32x2 r;
        #pragma unroll
        for (int k = 0; k < 16; ++k) {
            f32x2 x = pkmax0(h[k]);
            r = (k == 0) ? x * x : __builtin_elementwise_fma(x, x, r);
        }
        float red = tree_reduce(r.x + r.y);
        if (lane == 0) part0[wid] = red;
        asm volatile("s_waitcnt lgkmcnt(0)\n\ts_barrier" ::: "memory");
        Sprev = (part0[0] + part0[1]) + (part0[2] + part0[3]);
    }

    for (int rb = 0; rb < NBITS / 2; rb += 2) {
        #pragma unroll
        for (int u = 0; u < 2; ++u) {
            const int s = 2 * (rb + u);           // round rr = rb+u, steps (s, s+1)

            // this round's (i0,v0,i1,v1) — one ds_read_b128, consumed at decide
            int4 pvc = *(const int4*)(&pv[s]);

            // 3 candidate chains: A = h+d0, B = h+d1, C = (h+d0)+d1 (ref association)
            f32x2 ra, rbv, rc;
            #pragma unroll
            for (int k = 0; k < 16; ++k) {
                f32x2 va = h[k] + d0[u][k];
                f32x2 vb = h[k] + d1[k];
                f32x2 vc = va + d1[k];
                f32x2 xa = pkmax0(va), xb = pkmax0(vb), xc = pkmax0(vc);
                if (k == 0) { ra = xa * xa; rbv = xb * xb; rc = xc * xc; }
                else {
                    ra  = __builtin_elementwise_fma(xa, xa, ra);
                    rbv = __builtin_elementwise_fma(xb, xb, rbv);
                    rc  = __builtin_elementwise_fma(xc, xc, rc);
                }
            }
            float Ra = tree_reduce(ra.x + ra.y);
            float Rb = tree_reduce(rbv.x + rbv.y);
            float Rc = tree_reduce(rc.x + rc.y);
            if (lane == 0) {
                part[u][0][wid] = Ra;
                part[u][1][wid] = Rb;
                part[u][2][wid] = Rc;
            }
            asm volatile("s_waitcnt lgkmcnt(0)\n\ts_barrier" ::: "memory");

            // hidden under the part-read latency: next round's even deltas + loads
            GEN_D(d0[u ^ 1], wA[u ^ 1]);

            int li = (s + 4 < NBITS) ? s + 4 : NBITS - 2;   // even -> 16B aligned
            int4 pvn = *(const int4*)(&pv[li]);             // one ds_read_b128

            float4 pa = *(const float4*)(&part[u][0][0]);
            float4 pq = *(const float4*)(&part[u][1][0]);
            float4 pc = *(const float4*)(&part[u][2][0]);

            wA[u] = Bt[(size_t)pvn.x * 256 + t];  // round rr+2's words (2-round slack)
            wB[u] = Bt[(size_t)pvn.z * 256 + t];

            float Sa = (pa.x + pa.y) + (pa.z + pa.w);
            float Sb = (pq.x + pq.y) + (pq.z + pq.w);
            float Sc = (pc.x + pc.y) + (pc.z + pc.w);

            // accept iff E_new < E_prev  <=>  S_new > S_prev (ties reject)
            bool acc0 = Sa > Sprev;
            bool acc1 = acc0 ? (Sc > Sa) : (Sb > Sprev);
            Sprev = acc1 ? (acc0 ? Sc : Sb) : (acc0 ? Sa : Sprev);

            if (t == 0) {
                float v0 = __int_as_float(pvc.y), v1 = __int_as_float(pvc.w);
                out[pvc.x] = acc0 ? -v0 : v0;     // each i visited exactly once
                out[pvc.z] = acc1 ? -v1 : v1;
            }

            float f0s = acc0 ? 1.0f : 0.0f, f1s = acc1 ? 1.0f : 0.0f;
            f32x2 f0 = {f0s, f0s}, f1 = {f1s, f1s};
            #pragma unroll
            for (int k = 0; k < 16; ++k) {        // exact: d*1=d, d*0=+/-0
                f32x2 hh = __builtin_elementwise_fma(d0[u][k], f0, h[k]);
                h[k] = __builtin_elementwise_fma(d1[k], f1, hh);
            }

            // next round's odd deltas (d1 single-buffered; last use was the update)
            GEN_D(d1, wB[u ^ 1]);
        }
    }
}

extern "C" void kernel_launch(void* const* d_in, const int* in_sizes, int n_in,
                              void* d_out, int out_size, void* d_ws, size_t ws_size,
                              hipStream_t stream) {
    const float* W     = (const float*)d_in[0];
    const float* state = (const float*)d_in[1];
    const int*   perm  = (const int*)d_in[2];
    float*       out   = (float*)d_out;

    uint32_t* Bt = (uint32_t*)d_ws;
    float*    h0 = (float*)((char*)d_ws + (size_t)4096 * 256 * 4);

    pack_kernel<<<1024, 256, 0, stream>>>(W, state, Bt);
    gemv_kernel<<<2048, 256, 0, stream>>>(W, state, h0);
    seq_kernel<<<1, 256, 0, stream>>>(Bt, h0, state, perm, out);
}

// Round 12
// 2230.292 us; speedup vs baseline: 1.4840x; 1.0511x over previous
//
#include <hip/hip_runtime.h>
#include <cstdint>

#define NPAT 8192
#define NBITS 4096

typedef float f32x2 __attribute__((ext_vector_type(2)));
typedef unsigned int u32;

// ws layout:
//   [0, 4 MiB)      : Bt[i][t] delta-sign bits, uint32, i in [0,4096), t in [0,256)
//                     thread t: b = t>>2, a = t&3
//                     bit k     (k=0..15): sign of d for elem p = 128b + 2a     + 8k
//                     bit 16+k           : sign of d for elem p = 128b + 2a + 1 + 8k
//                     where d = -2*state[i]*W[p][i]  (state = ORIGINAL state; valid
//                     because perm visits each i exactly once). sign bit set => d<0.
//   [4 MiB, +32 KiB): h0 float[8192] (exact integers)

__global__ void pack_kernel(const float* __restrict__ W, const float* __restrict__ state,
                            uint32_t* __restrict__ Bt) {
    int b = blockIdx.x & 63;
    int i = (blockIdx.x >> 6) * 256 + threadIdx.x;
    uint32_t spre = (__float_as_uint(state[i]) >> 31) ^ 1u;
    uint32_t wd0 = 0, wd1 = 0, wd2 = 0, wd3 = 0;
    const float* base = W + (size_t)(128 * b) * NBITS + i;
    #pragma unroll
    for (int q = 0; q < 128; ++q) {
        uint32_t bit = (__float_as_uint(base[(size_t)q * NBITS]) >> 31) ^ spre;  // coalesced
        int j = q & 7, k = q >> 3;
        int a = j >> 1, hi = j & 1;
        uint32_t add = bit << (16 * hi + k);
        if (a == 0) wd0 |= add;
        else if (a == 1) wd1 |= add;
        else if (a == 2) wd2 |= add;
        else wd3 |= add;
    }
    *(uint4*)(Bt + (size_t)i * 256 + 4 * b) = make_uint4(wd0, wd1, wd2, wd3);
}

__global__ void gemv_kernel(const float* __restrict__ W, const float* __restrict__ state,
                            float* __restrict__ h0) {
    int wid = threadIdx.x >> 6, lane = threadIdx.x & 63;
    int p = blockIdx.x * 4 + wid;
    const float* row = W + (size_t)p * NBITS;
    float acc = 0.f;
    for (int k = lane; k < NBITS; k += 64) acc += row[k] * state[k];
    #pragma unroll
    for (int d = 1; d < 64; d <<= 1) acc += __shfl_xor(acc, d, 64);
    if (lane == 0) h0[p] = acc;
}

// Exact numpy-pairwise tree (proven bit-exact R1-R11, absmax 0).
__device__ __forceinline__ float tree_reduce(float x) {
    x = __uint_as_float(__builtin_amdgcn_update_dpp(__float_as_uint(x), __float_as_uint(x),
                                                    0xB1, 0xf, 0xf, false)) + x;   // quad xor1
    x = __uint_as_float(__builtin_amdgcn_update_dpp(__float_as_uint(x), __float_as_uint(x),
                                                    0x4E, 0xf, 0xf, false)) + x;   // quad xor2
    x = __uint_as_float(__builtin_amdgcn_update_dpp(__float_as_uint(x), __float_as_uint(x),
                                                    0x141, 0xf, 0xf, false)) + x;  // b^1
    x = __uint_as_float(__builtin_amdgcn_update_dpp(__float_as_uint(x), __float_as_uint(x),
                                                    0x140, 0xf, 0xf, false)) + x;  // b^2
#if __has_builtin(__builtin_amdgcn_permlane16_swap)
    {
        auto pr = __builtin_amdgcn_permlane16_swap(__float_as_uint(x), __float_as_uint(x),
                                                   false, false);
        x = __uint_as_float(pr[0]) + __uint_as_float(pr[1]);                        // lane^16
    }
#else
    x = __int_as_float(__builtin_amdgcn_ds_swizzle(__float_as_int(x), 0x401F)) + x;
#endif
#if __has_builtin(__builtin_amdgcn_permlane32_swap)
    {
        auto pr = __builtin_amdgcn_permlane32_swap(__float_as_uint(x), __float_as_uint(x),
                                                   false, false);
        x = __uint_as_float(pr[0]) + __uint_as_float(pr[1]);                        // lane^32
    }
#else
    x += __shfl_xor(x, 32, 64);
#endif
    return x;
}

__device__ __forceinline__ f32x2 pkmax0(f32x2 v) {
    f32x2 z = {0.0f, 0.0f};
    return __builtin_elementwise_max(v, z);
}

#define DLO(w, k) __uint_as_float((((w) << (31 - (k))) & 0x80000000u) | 0x40000000u)
#define DHI(w, k) __uint_as_float((((w) << (15 - (k))) & 0x80000000u) | 0x40000000u)

#define GEN_D(dst, w)                                                       \
    _Pragma("unroll")                                                       \
    for (int k = 0; k < 16; ++k) {                                          \
        dst[k] = (f32x2){DLO(w, k), DHI(w, k)};                             \
    }

__launch_bounds__(256, 1)
__global__ void seq_kernel(const uint32_t* __restrict__ Bt, const float* __restrict__ h0,
                           const float* __restrict__ state, const int* __restrict__ perm,
                           float* __restrict__ out) {
    __shared__ alignas(16) float part[2][4][4];   // [buf][wave][cand A,B,C,pad]
    __shared__ alignas(16) float part0[4];        // init-S only (race-free vs round 0)
    __shared__ alignas(16) int2 pv[NBITS];        // (i, bits(state[i])) in visit order

    const int t = threadIdx.x;
    const int b = t >> 2, a = t & 3;
    const int lane = t & 63, wid = t >> 6;

    for (int q = t; q < NBITS; q += 256) {
        int ii = perm[q];
        pv[q] = make_int2(ii, __float_as_int(state[ii]));
    }

    f32x2 h[16];
    #pragma unroll
    for (int k = 0; k < 16; ++k) h[k] = *(const f32x2*)(h0 + 128 * b + 2 * a + 8 * k);

    __syncthreads();

    // words for rounds 0..3 (steps 0..7); slot r&3 holds round r's pair
    u32 wA[4], wB[4];
    #pragma unroll
    for (int r = 0; r < 4; ++r) {
        wA[r] = Bt[(size_t)pv[2 * r].x * 256 + t];
        wB[r] = Bt[(size_t)pv[2 * r + 1].x * 256 + t];
    }

    f32x2 d0[2][16], d1[16];
    GEN_D(d0[0], wA[0]);           // round 0 even-step deltas
    GEN_D(d1, wB[0]);              // round 0 odd-step deltas

    float Sprev;
    {   // S(h_0), numpy-exact (dedicated buffer)
        f32x2 r;
        #pragma unroll
        for (int k = 0; k < 16; ++k) {
            f32x2 x = pkmax0(h[k]);
            r = (k == 0) ? x * x : __builtin_elementwise_fma(x, x, r);
        }
        float red = tree_reduce(r.x + r.y);
        if (lane == 0) part0[wid] = red;
        asm volatile("s_waitcnt lgkmcnt(0)\n\ts_barrier" ::: "memory");
        Sprev = (part0[0] + part0[1]) + (part0[2] + part0[3]);
    }

    for (int rb = 0; rb < NBITS / 2; rb += 4) {
        #pragma unroll
        for (int u = 0; u < 4; ++u) {
            const int rr = rb + u;             // round = steps (2rr, 2rr+1)
            const int s  = 2 * rr;
            const int pb = u & 1;              // buffers alternate; 2 barriers apart
            const int cu = u & 1;              // current d0 buffer

            // this round's (i0,v0,i1,v1) — one ds_read_b128, consumed at decide
            int4 pvc = *(const int4*)(&pv[s]);

            // 3 candidate chains: A = h+d0, B = h+d1, C = (h+d0)+d1 (ref association)
            f32x2 ra, rbv, rc;
            #pragma unroll
            for (int k = 0; k < 16; ++k) {
                f32x2 va = h[k] + d0[cu][k];
                f32x2 vb = h[k] + d1[k];
                f32x2 vc = va + d1[k];
                f32x2 xa = pkmax0(va), xb = pkmax0(vb), xc = pkmax0(vc);
                if (k == 0) { ra = xa * xa; rbv = xb * xb; rc = xc * xc; }
                else {
                    ra  = __builtin_elementwise_fma(xa, xa, ra);
                    rbv = __builtin_elementwise_fma(xb, xb, rbv);
                    rc  = __builtin_elementwise_fma(xc, xc, rc);
                }
            }
            float Ra = tree_reduce(ra.x + ra.y);
            float Rb = tree_reduce(rbv.x + rbv.y);
            float Rc = tree_reduce(rc.x + rc.y);
            if (lane == 0)
                *(float4*)(&part[pb][wid][0]) = make_float4(Ra, Rb, Rc, 0.0f);
            asm volatile("s_waitcnt lgkmcnt(0)\n\ts_barrier" ::: "memory");

            // post-barrier: issue part reads first ...
            float4 p0 = *(const float4*)(&part[pb][0][0]);
            float4 p1 = *(const float4*)(&part[pb][1][0]);
            float4 p2 = *(const float4*)(&part[pb][2][0]);
            float4 p3 = *(const float4*)(&part[pb][3][0]);

            // ... then fill the LDS-return window with accept-independent work
            GEN_D(d0[cu ^ 1], wA[(u + 1) & 3]);

            int li = (s + 8 < NBITS) ? s + 8 : NBITS - 2;   // even -> 16B aligned
            int4 pvn = *(const int4*)(&pv[li]);             // one ds_read_b128
            wA[u] = Bt[(size_t)pvn.x * 256 + t];            // round rr+4's words
            wB[u] = Bt[(size_t)pvn.z * 256 + t];            // (4-round slack)

            // decide (every thread redundantly; ties reject)
            float Sa = (p0.x + p1.x) + (p2.x + p3.x);
            float Sb = (p0.y + p1.y) + (p2.y + p3.y);
            float Sc = (p0.z + p1.z) + (p2.z + p3.z);
            bool acc0 = Sa > Sprev;
            bool acc1 = acc0 ? (Sc > Sa) : (Sb > Sprev);
            Sprev = acc1 ? (acc0 ? Sc : Sb) : (acc0 ? Sa : Sprev);

            if (t == 0) {
                float v0 = __int_as_float(pvc.y), v1 = __int_as_float(pvc.w);
                out[pvc.x] = acc0 ? -v0 : v0;               // each i exactly once
                out[pvc.z] = acc1 ? -v1 : v1;
            }

            float f0s = acc0 ? 1.0f : 0.0f, f1s = acc1 ? 1.0f : 0.0f;
            f32x2 f0 = {f0s, f0s}, f1 = {f1s, f1s};
            #pragma unroll
            for (int k = 0; k < 16; ++k) {     // exact: d*1=d, d*0=+/-0
                f32x2 hh = __builtin_elementwise_fma(d0[cu][k], f0, h[k]);
                h[k] = __builtin_elementwise_fma(d1[k], f1, hh);
            }

            // next round's odd deltas (d1 single-buffered; last use was the update)
            GEN_D(d1, wB[(u + 1) & 3]);
        }
    }
}

extern "C" void kernel_launch(void* const* d_in, const int* in_sizes, int n_in,
                              void* d_out, int out_size, void* d_ws, size_t ws_size,
                              hipStream_t stream) {
    const float* W     = (const float*)d_in[0];
    const float* state = (const float*)d_in[1];
    const int*   perm  = (const int*)d_in[2];
    float*       out   = (float*)d_out;

    uint32_t* Bt = (uint32_t*)d_ws;
    float*    h0 = (float*)((char*)d_ws + (size_t)4096 * 256 * 4);

    pack_kernel<<<1024, 256, 0, stream>>>(W, state, Bt);
    gemv_kernel<<<2048, 256, 0, stream>>>(W, state, h0);
    seq_kernel<<<1, 256, 0, stream>>>(Bt, h0, state, perm, out);
}

// Round 13
// 2082.399 us; speedup vs baseline: 1.5894x; 1.0710x over previous
//
#include <hip/hip_runtime.h>
#include <cstdint>

#define NPAT 8192
#define NBITS 4096

typedef float f32x2 __attribute__((ext_vector_type(2)));
typedef unsigned int u32;

// ws layout:
//   [0, 4 MiB)      : Bt[i][t] delta-sign bits, uint32, i in [0,4096), t in [0,256)
//                     thread t: b = t>>2, a = t&3
//                     bit k     (k=0..15): sign of d for elem p = 128b + 2a     + 8k
//                     bit 16+k           : sign of d for elem p = 128b + 2a + 1 + 8k
//                     where d = -2*state[i]*W[p][i] (state = ORIGINAL state; valid
//                     because perm visits each i exactly once)
//   [4 MiB, +32 KiB): h0 float[8192] (exact integers)

__global__ void pack_kernel(const float* __restrict__ W, const float* __restrict__ state,
                            uint32_t* __restrict__ Bt) {
    int b = blockIdx.x & 63;
    int i = (blockIdx.x >> 6) * 256 + threadIdx.x;
    uint32_t spre = (__float_as_uint(state[i]) >> 31) ^ 1u;
    uint32_t wd0 = 0, wd1 = 0, wd2 = 0, wd3 = 0;
    const float* base = W + (size_t)(128 * b) * NBITS + i;
    #pragma unroll
    for (int q = 0; q < 128; ++q) {
        uint32_t bit = (__float_as_uint(base[(size_t)q * NBITS]) >> 31) ^ spre;  // coalesced
        int j = q & 7, k = q >> 3;
        int a = j >> 1, hi = j & 1;
        uint32_t add = bit << (16 * hi + k);
        if (a == 0) wd0 |= add;
        else if (a == 1) wd1 |= add;
        else if (a == 2) wd2 |= add;
        else wd3 |= add;
    }
    *(uint4*)(Bt + (size_t)i * 256 + 4 * b) = make_uint4(wd0, wd1, wd2, wd3);
}

__global__ void gemv_kernel(const float* __restrict__ W, const float* __restrict__ state,
                            float* __restrict__ h0) {
    int wid = threadIdx.x >> 6, lane = threadIdx.x & 63;
    int p = blockIdx.x * 4 + wid;
    const float* row = W + (size_t)p * NBITS;
    float acc = 0.f;
    for (int k = lane; k < NBITS; k += 64) acc += row[k] * state[k];
    #pragma unroll
    for (int d = 1; d < 64; d <<= 1) acc += __shfl_xor(acc, d, 64);
    if (lane == 0) h0[p] = acc;
}

// Exact numpy-pairwise tree (mapping proven bit-exact in R1-R12, absmax 0).
__device__ __forceinline__ float tree_reduce(float x) {
    x = __uint_as_float(__builtin_amdgcn_update_dpp(__float_as_uint(x), __float_as_uint(x),
                                                    0xB1, 0xf, 0xf, false)) + x;   // quad xor1
    x = __uint_as_float(__builtin_amdgcn_update_dpp(__float_as_uint(x), __float_as_uint(x),
                                                    0x4E, 0xf, 0xf, false)) + x;   // quad xor2
    x = __uint_as_float(__builtin_amdgcn_update_dpp(__float_as_uint(x), __float_as_uint(x),
                                                    0x141, 0xf, 0xf, false)) + x;  // b^1
    x = __uint_as_float(__builtin_amdgcn_update_dpp(__float_as_uint(x), __float_as_uint(x),
                                                    0x140, 0xf, 0xf, false)) + x;  // b^2 (invariant)
#if __has_builtin(__builtin_amdgcn_permlane16_swap)
    {
        auto pr = __builtin_amdgcn_permlane16_swap(__float_as_uint(x), __float_as_uint(x),
                                                   false, false);
        x = __uint_as_float(pr[0]) + __uint_as_float(pr[1]);                        // lane^16
    }
#else
    x = __int_as_float(__builtin_amdgcn_ds_swizzle(__float_as_int(x), 0x401F)) + x;
#endif
#if __has_builtin(__builtin_amdgcn_permlane32_swap)
    {
        auto pr = __builtin_amdgcn_permlane32_swap(__float_as_uint(x), __float_as_uint(x),
                                                   false, false);
        x = __uint_as_float(pr[0]) + __uint_as_float(pr[1]);                        // lane^32
    }
#else
    x += __shfl_xor(x, 32, 64);
#endif
    return x;
}

__device__ __forceinline__ f32x2 pkmax0(f32x2 v) {
    f32x2 z = {0.0f, 0.0f};
    return __builtin_elementwise_max(v, z);
}

#define GEN_D(dst, w)                                                       \
    _Pragma("unroll")                                                       \
    for (int k = 0; k < 16; ++k) {                                          \
        u32 _lo = ((w << (31 - k)) & 0x80000000u) | 0x40000000u;            \
        u32 _hi = ((w << (15 - k)) & 0x80000000u) | 0x40000000u;            \
        dst[k] = (f32x2){__uint_as_float(_lo), __uint_as_float(_hi)};       \
    }

__launch_bounds__(256, 1)
__global__ void seq_kernel(const uint32_t* __restrict__ Bt, const float* __restrict__ h0,
                           const float* __restrict__ state, const int* __restrict__ perm,
                           float* __restrict__ out) {
    __shared__ alignas(16) float part[2][3][4];
    __shared__ alignas(16) float part0[4];
    __shared__ int2 pv[NBITS];                 // (i, bits(state[i])) in visit order

    const int t = threadIdx.x;
    const int b = t >> 2, a = t & 3;
    const int lane = t & 63, wid = t >> 6;

    for (int q = t; q < NBITS; q += 256) {
        int ii = perm[q];
        pv[q] = make_int2(ii, __float_as_int(state[ii]));
    }

    f32x2 h[16];
    #pragma unroll
    for (int k = 0; k < 16; ++k) h[k] = *(const f32x2*)(h0 + 128 * b + 2 * a + 8 * k);

    __syncthreads();

    // words for rounds 0..3 (steps 0..7); slot r&3 holds round r's pair
    u32 wA[4], wB[4];
    #pragma unroll
    for (int r = 0; r < 4; ++r) {
        wA[r] = Bt[(size_t)pv[2 * r].x * 256 + t];
        wB[r] = Bt[(size_t)pv[2 * r + 1].x * 256 + t];
    }

    f32x2 d0[2][16], d1[16];
    GEN_D(d0[0], wA[0]);           // round 0 even-step deltas
    GEN_D(d1, wB[0]);              // round 0 odd-step deltas

    float Sprev;
    {   // S(h_0), numpy-exact
        f32x2 r;
        #pragma unroll
        for (int k = 0; k < 16; ++k) {
            f32x2 x = pkmax0(h[k]);
            r = (k == 0) ? x * x : __builtin_elementwise_fma(x, x, r);
        }
        float red = tree_reduce(r.x + r.y);
        if (lane == 0) part0[wid] = red;
        asm volatile("s_waitcnt lgkmcnt(0)\n\ts_barrier" ::: "memory");
        float4 p = *(const float4*)(&part0[0]);
        Sprev = (p.x + p.y) + (p.z + p.w);
    }

    for (int rb = 0; rb < NBITS / 2; rb += 4) {
        #pragma unroll
        for (int u = 0; u < 4; ++u) {
            const int rr = rb + u;             // round = steps (2rr, 2rr+1)
            const int s  = 2 * rr;
            const int pb = rr & 1;
            const int cu = u & 1;              // current d0 buffer

            // (i, vi) for this round's decide/out — issued early, used late
            int2 pvi0 = pv[s];
            int2 pvi1 = pv[s + 1];

            // 3 candidate chains: A = h+d0, B = h+d1, C = (h+d0)+d1
            f32x2 ra, rbv, rc;
            #pragma unroll
            for (int k = 0; k < 16; ++k) {
                f32x2 va = h[k] + d0[cu][k];
                f32x2 vb = h[k] + d1[k];
                f32x2 vc = va + d1[k];         // same association as sequential ref
                f32x2 xa = pkmax0(va), xb = pkmax0(vb), xc = pkmax0(vc);
                if (k == 0) { ra = xa * xa; rbv = xb * xb; rc = xc * xc; }
                else {
                    ra  = __builtin_elementwise_fma(xa, xa, ra);
                    rbv = __builtin_elementwise_fma(xb, xb, rbv);
                    rc  = __builtin_elementwise_fma(xc, xc, rc);
                }
            }
            float Ra = tree_reduce(ra.x + ra.y);
            float Rb = tree_reduce(rbv.x + rbv.y);
            float Rc = tree_reduce(rc.x + rc.y);
            if (lane == 0) {
                part[pb][0][wid] = Ra;
                part[pb][1][wid] = Rb;
                part[pb][2][wid] = Rc;
            }
            asm volatile("s_waitcnt lgkmcnt(0)\n\ts_barrier" ::: "memory");

            // hidden under the part-read latency: next round's even deltas + loads
            GEN_D(d0[cu ^ 1], wA[(u + 1) & 3]);
            int li0 = s + 8 < NBITS ? s + 8 : NBITS - 1;
            int li1 = s + 9 < NBITS ? s + 9 : NBITS - 1;
            int iA = pv[li0].x, iB = pv[li1].x;

            float4 pa = *(const float4*)(&part[pb][0][0]);
            float4 pq = *(const float4*)(&part[pb][1][0]);
            float4 pc = *(const float4*)(&part[pb][2][0]);

            wA[u] = Bt[(size_t)iA * 256 + t];  // round rr+4's words (4-round slack)
            wB[u] = Bt[(size_t)iB * 256 + t];

            float Sa = (pa.x + pa.y) + (pa.z + pa.w);
            float Sb = (pq.x + pq.y) + (pq.z + pq.w);
            float Sc = (pc.x + pc.y) + (pc.z + pc.w);

            // accept iff E_new < E_prev  <=>  S_new > S_prev (ties reject)
            bool acc0 = Sa > Sprev;
            bool acc1 = acc0 ? (Sc > Sa) : (Sb > Sprev);
            Sprev = acc1 ? (acc0 ? Sc : Sb) : (acc0 ? Sa : Sprev);

            if (t == 0) {
                float v0 = __int_as_float(pvi0.y), v1 = __int_as_float(pvi1.y);
                out[pvi0.x] = acc0 ? -v0 : v0;
                out[pvi1.x] = acc1 ? -v1 : v1;
            }

            float f0s = acc0 ? 1.0f : 0.0f, f1s = acc1 ? 1.0f : 0.0f;
            f32x2 f0 = {f0s, f0s}, f1 = {f1s, f1s};
            #pragma unroll
            for (int k = 0; k < 16; ++k) {     // exact: d*1=d, d*0=+/-0, +0 adds are exact
                f32x2 hh = __builtin_elementwise_fma(d0[cu][k], f0, h[k]);
                h[k] = __builtin_elementwise_fma(d1[k], f1, hh);
            }

            // next round's odd deltas (d1 single-buffered; last use was the update above)
            GEN_D(d1, wB[(u + 1) & 3]);
        }
    }
}

extern "C" void kernel_launch(void* const* d_in, const int* in_sizes, int n_in,
                              void* d_out, int out_size, void* d_ws, size_t ws_size,
                              hipStream_t stream) {
    const float* W     = (const float*)d_in[0];
    const float* state = (const float*)d_in[1];
    const int*   perm  = (const int*)d_in[2];
    float*       out   = (float*)d_out;

    uint32_t* Bt = (uint32_t*)d_ws;
    float*    h0 = (float*)((char*)d_ws + (size_t)4096 * 256 * 4);

    pack_kernel<<<1024, 256, 0, stream>>>(W, state, Bt);
    gemv_kernel<<<2048, 256, 0, stream>>>(W, state, h0);
    seq_kernel<<<1, 256, 0, stream>>>(Bt, h0, state, perm, out);
}